// Round 7
// baseline (48.956 us; speedup 1.0000x reference)
//
#include <hip/hip_runtime.h>

// B=8, C=512, T=8192, RATIO=2, K=12
#define T_LEN 8192
#define C_N   512
#define BLOCK 256
#define OPT   8                       // outputs per thread
#define TCHUNK (BLOCK * OPT)          // 2048
#define NCHUNK 4
#define INV_2PI 0.15915494309189535f

typedef float f32x2 __attribute__((ext_vector_type(2)));

// Verified formulas (ground truth = rounds 0-6, all passing):
//   y[2i]   = 2 * sum_t wup[2t+1] * xc[i+2-t]   (t=0..5, xc = edge-clamped x)
//   y[2i+1] = 2 * sum_t wup[2t]   * xc[i+3-t]
//   snake:   y += sin(a*y)^2 / (a+1e-9)
//   out[n]  = sum_k wdn[k] * ypad[2n-5+k]       (ypad = edge-clamped y)
//
// Packed-f32 formulation (v_pk_fma_f32), R6 winner:
//   A_p := (yv[2p], yv[2p-1]), p=1..8, yv[u] = y[2N-6+u]
//   A_p = sum_t cpair[t] * splat(xr[7+p-t]),  cpair[t]=(u2[2t+1], u2[2t])
//   out[N+r] = sum_j dpair[j] (.) A_{r+j+1},  dpair[j]=(wdn[2j+1], wdn[2j])
//   A_{8+p} = shfl_down(A_p); lane 63 gathers lane-parallel halo yh
//     (lane v=2s+par: yh = y[2(N63+5+s)+par], taps xt[j]=xc[N63+2+s+par+j])
//
// R7: __launch_bounds__(256,8) -> 64-VGPR cap, 8 waves/SIMD, to convert the
// latency-bound "mem + VALU" sum into overlap. Coefficients are wave-uniform
// (SGPR-pair operands to v_pk_fma); xr dies before downsample; xt consumed
// right after upsample to shorten liveness.

__global__ __launch_bounds__(BLOCK, 8) void act1d_fused(
    const float* __restrict__ x,
    const float* __restrict__ alpha,
    const float* __restrict__ wup_g,
    const float* __restrict__ wdn_g,
    float* __restrict__ out)
{
    const int bx    = blockIdx.x;
    const int chunk = bx & (NCHUNK - 1);
    const int bc    = bx >> 2;              // row index b*C + c
    const int c     = bc & (C_N - 1);
    const int tid   = threadIdx.x;
    const int lane  = tid & 63;
    const int N     = chunk * TCHUNK + OPT * tid;   // first output of this lane
    const int N63   = N + OPT * (63 - lane);        // wave's lane-63 N (uniform)

    const float* __restrict__ xrow = x   + (size_t)bc * T_LEN;
    float*       __restrict__ orow = out + (size_t)bc * T_LEN;

    // ---- main x window: xr[u] = xc[N-8+u], u=0..15 (4x dwordx4) ----
    float xr[16];
    if (N >= 8) {
#pragma unroll
        for (int w = 0; w < 4; ++w) {
            const float4 t4 = *reinterpret_cast<const float4*>(xrow + N - 8 + 4 * w);
            xr[4 * w + 0] = t4.x;
            xr[4 * w + 1] = t4.y;
            xr[4 * w + 2] = t4.z;
            xr[4 * w + 3] = t4.w;
        }
    } else {   // only N==0: left edge clamp
#pragma unroll
        for (int u = 0; u < 16; ++u)
            xr[u] = xrow[max(N - 8 + u, 0)];
    }

    // ---- halo taps (lanes 0..10 meaningful, rest harmless) ----
    const int s_  = lane >> 1;
    const int par = lane & 1;
    const int hb  = N63 + 2 + s_ + par;
    float xt[6];
    if (N63 + 12 < T_LEN) {             // wave-uniform fast path
#pragma unroll
        for (int j = 0; j < 6; ++j)
            xt[j] = xrow[hb + j];
    } else {
#pragma unroll
        for (int j = 0; j < 6; ++j)
            xt[j] = xrow[min(hb + j, T_LEN - 1)];
    }

    // ---- uniform constants (wave-uniform -> SGPRs) ----
    f32x2 cpair[6], dpair[6];
#pragma unroll
    for (int t = 0; t < 6; ++t) {
        cpair[t] = (f32x2){ wup_g[2 * t + 1] + wup_g[2 * t + 1],
                            wup_g[2 * t]     + wup_g[2 * t] };
        dpair[t] = (f32x2){ wdn_g[2 * t + 1], wdn_g[2 * t] };
    }
    const float a     = __expf(alpha[c]);
    const float inv_a = 1.0f / (a + 1e-9f);
    const float ka    = a * INV_2PI;    // v_sin_f32 takes revolutions
    const f32x2 ka2   = (f32x2){ ka, ka };
    const f32x2 inva2 = (f32x2){ inv_a, inv_a };

    // ---- upsample, packed: A[p] = (yv[2p], yv[2p-1]), p=1..8 ----
    f32x2 A[14];
#pragma unroll
    for (int p = 1; p <= 8; ++p)
        A[p] = (f32x2){ 0.0f, 0.0f };
#pragma unroll
    for (int u = 3; u <= 15; ++u) {
        const f32x2 su = (f32x2){ xr[u], xr[u] };
#pragma unroll
        for (int t = 0; t < 6; ++t) {
            const int p = u - 7 + t;
            if (p >= 1 && p <= 8)
                A[p] = __builtin_elementwise_fma(cpair[t], su, A[p]);
        }
    }

    // ---- lane-parallel halo y (consume xt early; frees 6 regs) ----
    float yh = 0.0f;
#pragma unroll
    for (int j = 0; j < 6; ++j) {
        const float cj = par ? cpair[5 - j].y : cpair[5 - j].x;
        yh = fmaf(cj, xt[j], yh);
    }
    {
        const float s = __builtin_amdgcn_sinf(ka * yh);
        yh = fmaf(s * s, inv_a, yh);
    }

    // ---- snake, packed (scalar v_sin per half) ----
#pragma unroll
    for (int p = 1; p <= 8; ++p) {
        const f32x2 arg = A[p] * ka2;
        const f32x2 s   = (f32x2){ __builtin_amdgcn_sinf(arg.x),
                                   __builtin_amdgcn_sinf(arg.y) };
        A[p] = __builtin_elementwise_fma(s * s, inva2, A[p]);
    }

    // ---- left edge: ypad[m<0] = y[0]  (yv[1..5] = yv[6] when N==0) ----
    if (N == 0) {
        const float v = A[3].x;           // snaked yv[6]
        A[1] = (f32x2){ v, v };
        A[2] = (f32x2){ v, v };
        A[3].y = v;
    }

    // ---- halo pairs A[9..13]: shfl_down(A[1..5]); lane 63 via readlane ----
    const bool is63 = (lane == 63);
#pragma unroll
    for (int p = 1; p <= 5; ++p) {
        const float dx = __shfl_down(A[p].x, 1, 64);
        const float dy = __shfl_down(A[p].y, 1, 64);
        const float gx = __int_as_float(
            __builtin_amdgcn_readlane(__float_as_int(yh), 2 * p));
        const float gy = __int_as_float(
            __builtin_amdgcn_readlane(__float_as_int(yh), 2 * p - 1));
        A[8 + p] = (f32x2){ is63 ? gx : dx, is63 ? gy : dy };
    }

    // ---- right edge: ypad[m>16383] = y[16383]  (h[6..10] = h[5]) ----
    if (N == T_LEN - OPT) {
        const float h5 = A[11].y;
        A[11] = (f32x2){ h5, h5 };
        A[12] = (f32x2){ h5, h5 };
        A[13] = (f32x2){ h5, h5 };
    }

    // ---- downsample, packed: o_r = sum_j dpair[j] (.) A[r+j+1] ----
    float o[OPT];
#pragma unroll
    for (int r = 0; r < OPT; ++r) {
        f32x2 P = dpair[0] * A[r + 1];
#pragma unroll
        for (int j = 1; j < 6; ++j)
            P = __builtin_elementwise_fma(dpair[j], A[r + j + 1], P);
        o[r] = P.x + P.y;
    }

    *reinterpret_cast<float4*>(orow + N)     = make_float4(o[0], o[1], o[2], o[3]);
    *reinterpret_cast<float4*>(orow + N + 4) = make_float4(o[4], o[5], o[6], o[7]);
}

extern "C" void kernel_launch(void* const* d_in, const int* in_sizes, int n_in,
                              void* d_out, int out_size, void* d_ws, size_t ws_size,
                              hipStream_t stream)
{
    const float* x     = (const float*)d_in[0];
    const float* alpha = (const float*)d_in[1];
    const float* wup   = (const float*)d_in[2];
    const float* wdn   = (const float*)d_in[3];
    float*       out   = (float*)d_out;

    const int B_N  = out_size / (C_N * T_LEN);   // 8
    const int grid = B_N * C_N * NCHUNK;         // 16384

    act1d_fused<<<grid, BLOCK, 0, stream>>>(x, alpha, wup, wdn, out);
}

// Round 8
// 48.609 us; speedup vs baseline: 1.0071x; 1.0071x over previous
//
#include <hip/hip_runtime.h>

// B=8, C=512, T=8192, RATIO=2, K=12
#define T_LEN 8192
#define C_N   512
#define BLOCK 256
#define OPT   8                       // outputs per thread per chunk
#define TCHUNK (BLOCK * OPT)          // 2048
#define NCHUNK 4
#define INV_2PI 0.15915494309189535f

typedef float f32x2 __attribute__((ext_vector_type(2)));

// Verified formulas (ground truth = rounds 0-7, all passing):
//   y[2i]   = 2 * sum_t wup[2t+1] * xc[i+2-t]   (t=0..5, xc = edge-clamped x)
//   y[2i+1] = 2 * sum_t wup[2t]   * xc[i+3-t]
//   snake:   y += sin(a*y)^2 / (a+1e-9)
//   out[n]  = sum_k wdn[k] * ypad[2n-5+k]       (ypad = edge-clamped y)
//
// Packed-f32 formulation (v_pk_fma_f32), R6 winner:
//   A_p := (yv[2p], yv[2p-1]), p=1..8, yv[u] = y[2N-6+u]
//   A_p = sum_t cpair[t] * splat(xr[7+p-t]),  cpair[t]=(u2[2t+1], u2[2t])
//   out[N+r] = sum_j dpair[j] (.) A_{r+j+1},  dpair[j]=(wdn[2j+1], wdn[2j])
//   A_{8+p} = shfl_down(A_p); lane 63 gathers lane-parallel halo yh
//     (lane v=2s+par: yh = y[2(N63+5+s)+par], taps xt[j]=xc[N63+2+s+par+j])
//
// R8: persistent block per row (grid=4096), unrolled loop over 4 chunks with
// register double-buffered prefetch: chunk i+1's global loads issue BEFORE
// chunk i's compute -> each wave hides its own HBM latency. 4x longer block
// lifetime cuts dispatch churn; coefficient setup amortized 4x.

__global__ __launch_bounds__(BLOCK, 5) void act1d_fused(
    const float* __restrict__ x,
    const float* __restrict__ alpha,
    const float* __restrict__ wup_g,
    const float* __restrict__ wdn_g,
    float* __restrict__ out)
{
    const int bc   = blockIdx.x;            // row index b*C + c
    const int c    = bc & (C_N - 1);
    const int tid  = threadIdx.x;
    const int lane = tid & 63;

    const float* __restrict__ xrow = x   + (size_t)bc * T_LEN;
    float*       __restrict__ orow = out + (size_t)bc * T_LEN;

    // ---- prefetch chunk 0's x window: xr[u] = xc[0 + 8*tid - 8 + u] ----
    float xr[16];
    {
        const int N = OPT * tid;
        if (N >= 8) {
#pragma unroll
            for (int w = 0; w < 4; ++w) {
                const float4 t4 = *reinterpret_cast<const float4*>(xrow + N - 8 + 4 * w);
                xr[4 * w + 0] = t4.x;
                xr[4 * w + 1] = t4.y;
                xr[4 * w + 2] = t4.z;
                xr[4 * w + 3] = t4.w;
            }
        } else {   // tid==0 only: left edge clamp
#pragma unroll
            for (int u = 0; u < 16; ++u)
                xr[u] = xrow[max(N - 8 + u, 0)];
        }
    }

    // ---- uniform constants (wave-uniform -> SGPRs) ----
    f32x2 cpair[6], dpair[6];
#pragma unroll
    for (int t = 0; t < 6; ++t) {
        cpair[t] = (f32x2){ wup_g[2 * t + 1] + wup_g[2 * t + 1],
                            wup_g[2 * t]     + wup_g[2 * t] };
        dpair[t] = (f32x2){ wdn_g[2 * t + 1], wdn_g[2 * t] };
    }
    const float a     = __expf(alpha[c]);
    const float inv_a = 1.0f / (a + 1e-9f);
    const float ka    = a * INV_2PI;    // v_sin_f32 takes revolutions
    const f32x2 ka2   = (f32x2){ ka, ka };
    const f32x2 inva2 = (f32x2){ inv_a, inv_a };

    const int s_  = lane >> 1;
    const int par = lane & 1;

#pragma unroll
    for (int chunk = 0; chunk < NCHUNK; ++chunk) {
        const int N   = chunk * TCHUNK + OPT * tid;         // first output
        const int N63 = chunk * TCHUNK + OPT * (tid - lane + 63);

        // ---- halo taps for this chunk (neighbor-wave window -> L1/L2 hit;
        //      latency covered by the upsample below) ----
        const int hb = N63 + 2 + s_ + par;
        float xt[6];
        if (N63 + 12 < T_LEN) {           // wave-uniform fast path
#pragma unroll
            for (int j = 0; j < 6; ++j)
                xt[j] = xrow[hb + j];
        } else {
#pragma unroll
            for (int j = 0; j < 6; ++j)
                xt[j] = xrow[min(hb + j, T_LEN - 1)];
        }

        // ---- prefetch next chunk's window (N' >= 2048: no edge check) ----
        float xrN[16];
        if (chunk < NCHUNK - 1) {
            const float* pn = xrow + (chunk + 1) * TCHUNK + OPT * tid - 8;
#pragma unroll
            for (int w = 0; w < 4; ++w) {
                const float4 t4 = *reinterpret_cast<const float4*>(pn + 4 * w);
                xrN[4 * w + 0] = t4.x;
                xrN[4 * w + 1] = t4.y;
                xrN[4 * w + 2] = t4.z;
                xrN[4 * w + 3] = t4.w;
            }
        }

        // ---- upsample, packed: A[p] = (yv[2p], yv[2p-1]), p=1..8 ----
        f32x2 A[14];
#pragma unroll
        for (int p = 1; p <= 8; ++p)
            A[p] = (f32x2){ 0.0f, 0.0f };
#pragma unroll
        for (int u = 3; u <= 15; ++u) {
            const f32x2 su = (f32x2){ xr[u], xr[u] };
#pragma unroll
            for (int t = 0; t < 6; ++t) {
                const int p = u - 7 + t;
                if (p >= 1 && p <= 8)
                    A[p] = __builtin_elementwise_fma(cpair[t], su, A[p]);
            }
        }

        // ---- lane-parallel halo y (lane v<11 real, others harmless) ----
        float yh = 0.0f;
#pragma unroll
        for (int j = 0; j < 6; ++j) {
            const float cj = par ? cpair[5 - j].y : cpair[5 - j].x;
            yh = fmaf(cj, xt[j], yh);
        }
        {
            const float s = __builtin_amdgcn_sinf(ka * yh);
            yh = fmaf(s * s, inv_a, yh);
        }

        // ---- snake, packed (scalar v_sin per half) ----
#pragma unroll
        for (int p = 1; p <= 8; ++p) {
            const f32x2 arg = A[p] * ka2;
            const f32x2 s   = (f32x2){ __builtin_amdgcn_sinf(arg.x),
                                       __builtin_amdgcn_sinf(arg.y) };
            A[p] = __builtin_elementwise_fma(s * s, inva2, A[p]);
        }

        // ---- left edge: ypad[m<0] = y[0]  (yv[1..5]=yv[6], only N==0) ----
        if (N == 0) {
            const float v = A[3].x;       // snaked yv[6]
            A[1] = (f32x2){ v, v };
            A[2] = (f32x2){ v, v };
            A[3].y = v;
        }

        // ---- halo pairs A[9..13]: shfl_down(A[1..5]); lane63 readlane ----
        const bool is63 = (lane == 63);
#pragma unroll
        for (int p = 1; p <= 5; ++p) {
            const float dx = __shfl_down(A[p].x, 1, 64);
            const float dy = __shfl_down(A[p].y, 1, 64);
            const float gx = __int_as_float(
                __builtin_amdgcn_readlane(__float_as_int(yh), 2 * p));
            const float gy = __int_as_float(
                __builtin_amdgcn_readlane(__float_as_int(yh), 2 * p - 1));
            A[8 + p] = (f32x2){ is63 ? gx : dx, is63 ? gy : dy };
        }

        // ---- right edge: ypad[m>16383] = y[16383]  (h[6..10]=h[5]) ----
        if (N == T_LEN - OPT) {
            const float h5 = A[11].y;
            A[11] = (f32x2){ h5, h5 };
            A[12] = (f32x2){ h5, h5 };
            A[13] = (f32x2){ h5, h5 };
        }

        // ---- downsample, packed: o_r = sum_j dpair[j] (.) A[r+j+1] ----
        float o[OPT];
#pragma unroll
        for (int r = 0; r < OPT; ++r) {
            f32x2 P = dpair[0] * A[r + 1];
#pragma unroll
            for (int j = 1; j < 6; ++j)
                P = __builtin_elementwise_fma(dpair[j], A[r + j + 1], P);
            o[r] = P.x + P.y;
        }

        *reinterpret_cast<float4*>(orow + N)     = make_float4(o[0], o[1], o[2], o[3]);
        *reinterpret_cast<float4*>(orow + N + 4) = make_float4(o[4], o[5], o[6], o[7]);

        // ---- rotate prefetch buffer (register renames after unroll) ----
        if (chunk < NCHUNK - 1) {
#pragma unroll
            for (int u = 0; u < 16; ++u)
                xr[u] = xrN[u];
        }
    }
}

extern "C" void kernel_launch(void* const* d_in, const int* in_sizes, int n_in,
                              void* d_out, int out_size, void* d_ws, size_t ws_size,
                              hipStream_t stream)
{
    const float* x     = (const float*)d_in[0];
    const float* alpha = (const float*)d_in[1];
    const float* wup   = (const float*)d_in[2];
    const float* wdn   = (const float*)d_in[3];
    float*       out   = (float*)d_out;

    const int B_N  = out_size / (C_N * T_LEN);   // 8
    const int grid = B_N * C_N;                  // 4096: one block per row

    act1d_fused<<<grid, BLOCK, 0, stream>>>(x, alpha, wup, wdn, out);
}

// Round 9
// 48.224 us; speedup vs baseline: 1.0152x; 1.0080x over previous
//
#include <hip/hip_runtime.h>

// B=8, C=512, T=8192, RATIO=2, K=12
#define T_LEN 8192
#define C_N   512
#define BLOCK 256
#define OPT   8                       // outputs per thread per chunk
#define TCHUNK (BLOCK * OPT)          // 2048
#define NCHUNK 4
#define INV_2PI 0.15915494309189535f

typedef float f32x2 __attribute__((ext_vector_type(2)));

// Verified formulas (ground truth = rounds 0-8, all passing):
//   y[2i]   = 2 * sum_t wup[2t+1] * xc[i+2-t]   (t=0..5, xc = edge-clamped x)
//   y[2i+1] = 2 * sum_t wup[2t]   * xc[i+3-t]
//   snake:   y += sin(a*y)^2 / (a+1e-9)
//   out[n]  = sum_k wdn[k] * ypad[2n-5+k]       (ypad = edge-clamped y)
//
// Packed-f32 formulation (v_pk_fma_f32), R6 winner:
//   A_p := (yv[2p], yv[2p-1]), p=1..8, yv[u] = y[2N-6+u]
//   A_p = sum_t cpair[t] * splat(xr[7+p-t]),  cpair[t]=(u2[2t+1], u2[2t])
//   out[N+r] = sum_j dpair[j] (.) A_{r+j+1},  dpair[j]=(wdn[2j+1], wdn[2j])
//   A_{8+p} = shfl_down(A_p); lane 63 gathers lane-parallel halo yh
//     (lane v=2s+par: yh = y[2(N63+5+s)+par], taps xt[j]=xc[N63+2+s+par+j])
//
// R9: R8's persistent-row block + FORCED cross-chunk prefetch. R8's VGPR=36
// proved the compiler sank the prefetch loads to their uses. Here chunk i+1's
// ENTIRE memory (4x dwordx4 + 6 halo taps) is issued before chunk i's
// compute, pinned by sched_barrier(0) + asm memory clobber; the xr=xrN rename
// (renamed away by unroll) puts vmcnt waits at chunk i+1's first use.
// Verification handle: VGPR_Count must jump to ~80-110.

__global__ __launch_bounds__(BLOCK, 4) void act1d_fused(
    const float* __restrict__ x,
    const float* __restrict__ alpha,
    const float* __restrict__ wup_g,
    const float* __restrict__ wdn_g,
    float* __restrict__ out)
{
    const int bc   = blockIdx.x;            // row index b*C + c
    const int c    = bc & (C_N - 1);
    const int tid  = threadIdx.x;
    const int lane = tid & 63;
    const int s_   = lane >> 1;
    const int par  = lane & 1;
    const int b63  = OPT * (tid - lane + 63);   // lane-63 N offset (wave-uniform)

    const float* __restrict__ xrow = x   + (size_t)bc * T_LEN;
    float*       __restrict__ orow = out + (size_t)bc * T_LEN;

    // ---- prologue: chunk 0's full memory ----
    float xr[16], xt[6];
    {
        const int N = OPT * tid;
        if (N >= 8) {
#pragma unroll
            for (int w = 0; w < 4; ++w) {
                const float4 t4 = *reinterpret_cast<const float4*>(xrow + N - 8 + 4 * w);
                xr[4 * w + 0] = t4.x;
                xr[4 * w + 1] = t4.y;
                xr[4 * w + 2] = t4.z;
                xr[4 * w + 3] = t4.w;
            }
        } else {   // tid==0 only: left edge clamp
#pragma unroll
            for (int u = 0; u < 16; ++u)
                xr[u] = xrow[max(N - 8 + u, 0)];
        }
        const int hb = b63 + 2 + s_ + par;      // chunk 0: always in range
#pragma unroll
        for (int j = 0; j < 6; ++j)
            xt[j] = xrow[hb + j];
    }

    // ---- uniform constants (wave-uniform -> SGPRs) ----
    f32x2 cpair[6], dpair[6];
#pragma unroll
    for (int t = 0; t < 6; ++t) {
        cpair[t] = (f32x2){ wup_g[2 * t + 1] + wup_g[2 * t + 1],
                            wup_g[2 * t]     + wup_g[2 * t] };
        dpair[t] = (f32x2){ wdn_g[2 * t + 1], wdn_g[2 * t] };
    }
    const float a     = __expf(alpha[c]);
    const float inv_a = 1.0f / (a + 1e-9f);
    const float ka    = a * INV_2PI;    // v_sin_f32 takes revolutions
    const f32x2 ka2   = (f32x2){ ka, ka };
    const f32x2 inva2 = (f32x2){ inv_a, inv_a };

#pragma unroll
    for (int chunk = 0; chunk < NCHUNK; ++chunk) {
        const int N   = chunk * TCHUNK + OPT * tid;     // first output
        const int N63 = chunk * TCHUNK + b63;

        // ---- prefetch chunk+1's ENTIRE memory (issue-early) ----
        float xrN[16], xtN[6];
        if (chunk < NCHUNK - 1) {
            const float* pn = xrow + (chunk + 1) * TCHUNK + OPT * tid - 8;
#pragma unroll
            for (int w = 0; w < 4; ++w) {
                const float4 t4 = *reinterpret_cast<const float4*>(pn + 4 * w);
                xrN[4 * w + 0] = t4.x;
                xrN[4 * w + 1] = t4.y;
                xrN[4 * w + 2] = t4.z;
                xrN[4 * w + 3] = t4.w;
            }
            const int N63n = N63 + TCHUNK;
            const int hbn  = N63n + 2 + s_ + par;
            if (N63n + 12 < T_LEN) {        // wave-uniform fast path
#pragma unroll
                for (int j = 0; j < 6; ++j)
                    xtN[j] = xrow[hbn + j];
            } else {                         // last wave of chunk 3 only
#pragma unroll
                for (int j = 0; j < 6; ++j)
                    xtN[j] = xrow[min(hbn + j, T_LEN - 1)];
            }
        }

        // ---- pin: loads stay above, compute below (wait lands at use) ----
        asm volatile("" ::: "memory");
        __builtin_amdgcn_sched_barrier(0);

        // ---- upsample, packed: A[p] = (yv[2p], yv[2p-1]), p=1..8 ----
        f32x2 A[14];
#pragma unroll
        for (int p = 1; p <= 8; ++p)
            A[p] = (f32x2){ 0.0f, 0.0f };
#pragma unroll
        for (int u = 3; u <= 15; ++u) {
            const f32x2 su = (f32x2){ xr[u], xr[u] };
#pragma unroll
            for (int t = 0; t < 6; ++t) {
                const int p = u - 7 + t;
                if (p >= 1 && p <= 8)
                    A[p] = __builtin_elementwise_fma(cpair[t], su, A[p]);
            }
        }

        // ---- lane-parallel halo y (lane v<11 real, others harmless) ----
        float yh = 0.0f;
#pragma unroll
        for (int j = 0; j < 6; ++j) {
            const float cj = par ? cpair[5 - j].y : cpair[5 - j].x;
            yh = fmaf(cj, xt[j], yh);
        }
        {
            const float s = __builtin_amdgcn_sinf(ka * yh);
            yh = fmaf(s * s, inv_a, yh);
        }

        // ---- snake, packed (scalar v_sin per half) ----
#pragma unroll
        for (int p = 1; p <= 8; ++p) {
            const f32x2 arg = A[p] * ka2;
            const f32x2 s   = (f32x2){ __builtin_amdgcn_sinf(arg.x),
                                       __builtin_amdgcn_sinf(arg.y) };
            A[p] = __builtin_elementwise_fma(s * s, inva2, A[p]);
        }

        // ---- left edge: ypad[m<0] = y[0]  (yv[1..5]=yv[6], only N==0) ----
        if (N == 0) {
            const float v = A[3].x;       // snaked yv[6]
            A[1] = (f32x2){ v, v };
            A[2] = (f32x2){ v, v };
            A[3].y = v;
        }

        // ---- halo pairs A[9..13]: shfl_down(A[1..5]); lane63 readlane ----
        const bool is63 = (lane == 63);
#pragma unroll
        for (int p = 1; p <= 5; ++p) {
            const float dx = __shfl_down(A[p].x, 1, 64);
            const float dy = __shfl_down(A[p].y, 1, 64);
            const float gx = __int_as_float(
                __builtin_amdgcn_readlane(__float_as_int(yh), 2 * p));
            const float gy = __int_as_float(
                __builtin_amdgcn_readlane(__float_as_int(yh), 2 * p - 1));
            A[8 + p] = (f32x2){ is63 ? gx : dx, is63 ? gy : dy };
        }

        // ---- right edge: ypad[m>16383] = y[16383]  (h[6..10]=h[5]) ----
        if (N == T_LEN - OPT) {
            const float h5 = A[11].y;
            A[11] = (f32x2){ h5, h5 };
            A[12] = (f32x2){ h5, h5 };
            A[13] = (f32x2){ h5, h5 };
        }

        // ---- downsample, packed: o_r = sum_j dpair[j] (.) A[r+j+1] ----
        float o[OPT];
#pragma unroll
        for (int r = 0; r < OPT; ++r) {
            f32x2 P = dpair[0] * A[r + 1];
#pragma unroll
            for (int j = 1; j < 6; ++j)
                P = __builtin_elementwise_fma(dpair[j], A[r + j + 1], P);
            o[r] = P.x + P.y;
        }

        *reinterpret_cast<float4*>(orow + N)     = make_float4(o[0], o[1], o[2], o[3]);
        *reinterpret_cast<float4*>(orow + N + 4) = make_float4(o[4], o[5], o[6], o[7]);

        // ---- rotate prefetch buffers (renamed away by full unroll) ----
        if (chunk < NCHUNK - 1) {
#pragma unroll
            for (int u = 0; u < 16; ++u)
                xr[u] = xrN[u];
#pragma unroll
            for (int j = 0; j < 6; ++j)
                xt[j] = xtN[j];
        }
    }
}

extern "C" void kernel_launch(void* const* d_in, const int* in_sizes, int n_in,
                              void* d_out, int out_size, void* d_ws, size_t ws_size,
                              hipStream_t stream)
{
    const float* x     = (const float*)d_in[0];
    const float* alpha = (const float*)d_in[1];
    const float* wup   = (const float*)d_in[2];
    const float* wdn   = (const float*)d_in[3];
    float*       out   = (float*)d_out;

    const int B_N  = out_size / (C_N * T_LEN);   // 8
    const int grid = B_N * C_N;                  // 4096: one block per row

    act1d_fused<<<grid, BLOCK, 0, stream>>>(x, alpha, wup, wdn, out);
}